// Round 9
// baseline (273.634 us; speedup 1.0000x reference)
//
#include <hip/hip_runtime.h>

#define LR_C 0.01f
#define NB 8
#define NTOK 1024
#define DD 256
#define CH 8
#define NCHUNK (NTOK / CH)   // 128

// DPP add: s += dpp_move(s, ctrl), bound_ctrl=true
#define DPP_ADD(x, ctrl) \
    ((x) + __int_as_float(__builtin_amdgcn_update_dpp( \
        0, __float_as_int(x), (ctrl), 0xF, 0xF, true)))

// Full 64-lane all-lanes sum (proven in gram kernel R4-R6).
#define REDUCE_ALL64(s) do { \
    s = DPP_ADD(s, 0xB1); \
    s = DPP_ADD(s, 0x4E); \
    s = DPP_ADD(s, 0x141); \
    s = DPP_ADD(s, 0x140); \
    s += __shfl_xor(s, 16, 64); \
    s += __shfl_xor(s, 32, 64); \
} while (0)

// Async global->LDS staging (no VGPR round-trip; proven correct in R6).
__device__ __forceinline__ void gload16(const float* g, float* l) {
    __builtin_amdgcn_global_load_lds(
        (const __attribute__((address_space(1))) unsigned int*)g,
        (__attribute__((address_space(3))) unsigned int*)l, 16, 0, 0);
}
__device__ __forceinline__ void gload4(const float* g, float* l) {
    __builtin_amdgcn_global_load_lds(
        (const __attribute__((address_space(1))) unsigned int*)g,
        (__attribute__((address_space(3))) unsigned int*)l, 4, 0, 0);
}

// ---------------------------------------------------------------------------
// GEMM1: C[m][n] = sum_k A[m][k]*B[n][k]. 128x64 tile, BK=16, 512 thr.
// (unchanged from R6 — passed)
// ---------------------------------------------------------------------------
#define GM 128
#define GN 64
#define GK 16

__global__ __launch_bounds__(512) void gemm_abt_kernel(
    const float* __restrict__ A, const float* __restrict__ B,
    float* __restrict__ C)
{
    __shared__ float As[GK][GM + 4];
    __shared__ float Bs[GK][GN + 4];
    const int t    = threadIdx.x;
    const int arow = t >> 2, ak = (t & 3) * 4;
    const int brow = t >> 2, bk = (t & 3) * 4;
    const int tx   = t & 15, ty = t >> 4;

    const float* Ap = A + (size_t)(blockIdx.x * GM + arow) * DD + ak;
    const float* Bp = B + (size_t)(blockIdx.y * GN + (t < 256 ? brow : 0)) * DD + bk;

    float4 acc[4];
    #pragma unroll
    for (int i = 0; i < 4; ++i) acc[i] = make_float4(0.f, 0.f, 0.f, 0.f);

    float4 a0 = *reinterpret_cast<const float4*>(Ap);
    float4 b0 = *reinterpret_cast<const float4*>(Bp);

    for (int k0 = 0; k0 < DD; k0 += GK) {
        __syncthreads();
        As[ak + 0][arow] = a0.x; As[ak + 1][arow] = a0.y;
        As[ak + 2][arow] = a0.z; As[ak + 3][arow] = a0.w;
        if (t < 256) {
            Bs[bk + 0][brow] = b0.x; Bs[bk + 1][brow] = b0.y;
            Bs[bk + 2][brow] = b0.z; Bs[bk + 3][brow] = b0.w;
        }
        __syncthreads();
        if (k0 + GK < DD) {
            a0 = *reinterpret_cast<const float4*>(Ap + k0 + GK);
            b0 = *reinterpret_cast<const float4*>(Bp + k0 + GK);
        }
        #pragma unroll
        for (int k = 0; k < GK; ++k) {
            float4 av = *reinterpret_cast<const float4*>(&As[k][ty * 4]);
            float4 bv = *reinterpret_cast<const float4*>(&Bs[k][tx * 4]);
            acc[0].x = fmaf(av.x, bv.x, acc[0].x); acc[0].y = fmaf(av.x, bv.y, acc[0].y);
            acc[0].z = fmaf(av.x, bv.z, acc[0].z); acc[0].w = fmaf(av.x, bv.w, acc[0].w);
            acc[1].x = fmaf(av.y, bv.x, acc[1].x); acc[1].y = fmaf(av.y, bv.y, acc[1].y);
            acc[1].z = fmaf(av.y, bv.z, acc[1].z); acc[1].w = fmaf(av.y, bv.w, acc[1].w);
            acc[2].x = fmaf(av.z, bv.x, acc[2].x); acc[2].y = fmaf(av.z, bv.y, acc[2].y);
            acc[2].z = fmaf(av.z, bv.z, acc[2].z); acc[2].w = fmaf(av.z, bv.w, acc[2].w);
            acc[3].x = fmaf(av.w, bv.x, acc[3].x); acc[3].y = fmaf(av.w, bv.y, acc[3].y);
            acc[3].z = fmaf(av.w, bv.z, acc[3].z); acc[3].w = fmaf(av.w, bv.w, acc[3].w);
        }
    }
    #pragma unroll
    for (int i = 0; i < 4; ++i) {
        float* cp = C + (size_t)(blockIdx.x * GM + ty * 4 + i) * DD
                      + blockIdx.y * GN + tx * 4;
        *reinterpret_cast<float4*>(cp) = acc[i];
    }
}

// ---------------------------------------------------------------------------
// GEMM2: C[b*1024+t][n] = sum_k PT[b][k][t]*B[n][k]. (unchanged from R6)
// ---------------------------------------------------------------------------
__global__ __launch_bounds__(512) void gemm_pt_kernel(
    const float* __restrict__ PT, const float* __restrict__ B,
    float* __restrict__ C)
{
    __shared__ float As[GK][GM + 4];
    __shared__ float Bs[GK][GN + 4];
    const int t  = threadIdx.x;
    const int mb = blockIdx.x;
    const int b  = mb >> 3;
    const int t0 = (mb & 7) * GM;

    const int krow = t >> 5, tcol = (t & 31) * 4;
    const int brow = t >> 2, bk   = (t & 3) * 4;
    const int tx   = t & 15, ty   = t >> 4;

    const float* Ap = PT + (size_t)b * DD * NTOK + (size_t)krow * NTOK + t0 + tcol;
    const float* Bp = B + (size_t)(blockIdx.y * GN + (t < 256 ? brow : 0)) * DD + bk;

    float4 acc[4];
    #pragma unroll
    for (int i = 0; i < 4; ++i) acc[i] = make_float4(0.f, 0.f, 0.f, 0.f);

    float4 a0 = *reinterpret_cast<const float4*>(Ap);
    float4 b0 = *reinterpret_cast<const float4*>(Bp);

    for (int k0 = 0; k0 < DD; k0 += GK) {
        __syncthreads();
        *reinterpret_cast<float4*>(&As[krow][tcol]) = a0;
        if (t < 256) {
            Bs[bk + 0][brow] = b0.x; Bs[bk + 1][brow] = b0.y;
            Bs[bk + 2][brow] = b0.z; Bs[bk + 3][brow] = b0.w;
        }
        __syncthreads();
        if (k0 + GK < DD) {
            a0 = *reinterpret_cast<const float4*>(Ap + (size_t)(k0 + GK) * NTOK);
            b0 = *reinterpret_cast<const float4*>(Bp + k0 + GK);
        }
        #pragma unroll
        for (int k = 0; k < GK; ++k) {
            float4 av = *reinterpret_cast<const float4*>(&As[k][ty * 4]);
            float4 bv = *reinterpret_cast<const float4*>(&Bs[k][tx * 4]);
            acc[0].x = fmaf(av.x, bv.x, acc[0].x); acc[0].y = fmaf(av.x, bv.y, acc[0].y);
            acc[0].z = fmaf(av.x, bv.z, acc[0].z); acc[0].w = fmaf(av.x, bv.w, acc[0].w);
            acc[1].x = fmaf(av.y, bv.x, acc[1].x); acc[1].y = fmaf(av.y, bv.y, acc[1].y);
            acc[1].z = fmaf(av.y, bv.z, acc[1].z); acc[1].w = fmaf(av.y, bv.w, acc[1].w);
            acc[2].x = fmaf(av.z, bv.x, acc[2].x); acc[2].y = fmaf(av.z, bv.y, acc[2].y);
            acc[2].z = fmaf(av.z, bv.z, acc[2].z); acc[2].w = fmaf(av.z, bv.w, acc[2].w);
            acc[3].x = fmaf(av.w, bv.x, acc[3].x); acc[3].y = fmaf(av.w, bv.y, acc[3].y);
            acc[3].z = fmaf(av.w, bv.z, acc[3].z); acc[3].w = fmaf(av.w, bv.w, acc[3].w);
        }
    }
    #pragma unroll
    for (int i = 0; i < 4; ++i) {
        float* cp = C + (size_t)(b * NTOK + t0 + ty * 4 + i) * DD
                      + blockIdx.y * GN + tx * 4;
        *reinterpret_cast<float4*>(cp) = acc[i];
    }
}

// ---------------------------------------------------------------------------
// Gram: c_ij = h_i . h_j for j<i in chunk of 8 (unchanged; passed R4-R6).
// ---------------------------------------------------------------------------
__global__ __launch_bounds__(128) void gram_kernel(
    const float* __restrict__ H, float* __restrict__ Gram)
{
    const int blk  = blockIdx.x;
    const int b    = blk & 7;
    const int chk  = blk >> 3;
    const int w    = threadIdx.x >> 6;
    const int lane = threadIdx.x & 63;
    const float* Hc = H + ((size_t)b * NTOK + (size_t)chk * CH) * DD + lane * 4;

    float4 h[CH];
    #pragma unroll
    for (int i = 0; i < CH; ++i)
        h[i] = *reinterpret_cast<const float4*>(Hc + (size_t)i * DD);

    float sel = 0.f;
    #pragma unroll
    for (int i = 1; i < CH; ++i) {
        #pragma unroll
        for (int j = 0; j < i; ++j) {
            const int idx = i * (i - 1) / 2 + j;
            if ((idx & 1) == w) {
                float s = h[j].x * h[i].x;
                s = fmaf(h[j].y, h[i].y, s);
                s = fmaf(h[j].z, h[i].z, s);
                s = fmaf(h[j].w, h[i].w, s);
                REDUCE_ALL64(s);
                sel = (lane == idx) ? s : sel;
            }
        }
    }
    if (lane < 28 && (lane & 1) == w)
        Gram[((size_t)b * NCHUNK + chk) * 32 + lane] = sel;
}

// ---------------------------------------------------------------------------
// Chunked scan: 2048 blocks x 64 thr (1 wave, no barriers, XCD-swizzled).
// global_load_lds double-buffer with COUNTED vmcnt(10) wait: the next chunk's
// 10 staging ops stay in flight across this chunk's compute (T4).
// Reduce: batched 64-lane butterfly (no LDS transpose, no readlane).
// ---------------------------------------------------------------------------
#define STAGE_CHUNK(nc, pb) do { \
    const float* hs_ = hbase + (size_t)(nc) * (CH * DD); \
    gload16(hs_ + 0 * DD, &HB[pb][0][0]); \
    gload16(hs_ + 1 * DD, &HB[pb][1][0]); \
    gload16(hs_ + 2 * DD, &HB[pb][2][0]); \
    gload16(hs_ + 3 * DD, &HB[pb][3][0]); \
    gload16(hs_ + 4 * DD, &HB[pb][4][0]); \
    gload16(hs_ + 5 * DD, &HB[pb][5][0]); \
    gload16(hs_ + 6 * DD, &HB[pb][6][0]); \
    gload16(hs_ + 7 * DD, &HB[pb][7][0]); \
    gload4(tbase + (size_t)(nc) * (CH * DD), &TB[pb][0]); \
    gload4(gbase + (size_t)(nc) * 32, &GB[pb][0]); \
} while (0)

#define SCAN_BODY(ch, par) do { \
    const int nc_ = ((ch) + 1 < NCHUNK) ? (ch) + 1 : NCHUNK - 1; \
    STAGE_CHUNK(nc_, (par) ^ 1); \
    /* previous stage (10 ops) + older store drain; new stage stays in flight */ \
    asm volatile("s_waitcnt vmcnt(10)" ::: "memory"); \
    __builtin_amdgcn_sched_barrier(0); \
    float4 hh[CH]; float s[CH]; \
    _Pragma("unroll") \
    for (int i_ = 0; i_ < CH; ++i_) { \
        hh[i_] = *reinterpret_cast<const float4*>(&HB[par][i_][lane * 4]); \
        float sv_ = hh[i_].x * th.x; \
        sv_ = fmaf(hh[i_].y, th.y, sv_); \
        sv_ = fmaf(hh[i_].z, th.z, sv_); \
        sv_ = fmaf(hh[i_].w, th.w, sv_); \
        s[i_] = sv_; \
    } \
    _Pragma("unroll") \
    for (int i_ = 0; i_ < CH; ++i_) { REDUCE_ALL64(s[i_]); } \
    float4 tg0_ = *reinterpret_cast<const float4*>(&TB[par][0]); \
    float4 tg1_ = *reinterpret_cast<const float4*>(&TB[par][4]); \
    float lt_[CH] = {LR_C * tg0_.x, LR_C * tg0_.y, LR_C * tg0_.z, LR_C * tg0_.w, \
                     LR_C * tg1_.x, LR_C * tg1_.y, LR_C * tg1_.z, LR_C * tg1_.w}; \
    float gv_[28]; \
    _Pragma("unroll") \
    for (int q_ = 0; q_ < 7; ++q_) \
        *reinterpret_cast<float4*>(&gv_[q_ * 4]) = \
            *reinterpret_cast<const float4*>(&GB[par][q_ * 4]); \
    float e_[CH], p_[CH]; \
    _Pragma("unroll") \
    for (int i_ = 0; i_ < CH; ++i_) { \
        float pv_ = s[i_]; \
        _Pragma("unroll") \
        for (int j_ = 0; j_ < i_; ++j_) \
            pv_ = fmaf(e_[j_], gv_[i_ * (i_ - 1) / 2 + j_], pv_); \
        p_[i_] = pv_; \
        e_[i_] = fmaf(-LR_C, pv_, lt_[i_]); \
    } \
    _Pragma("unroll") \
    for (int j_ = 0; j_ < CH; ++j_) { \
        th.x = fmaf(e_[j_], hh[j_].x, th.x); \
        th.y = fmaf(e_[j_], hh[j_].y, th.y); \
        th.z = fmaf(e_[j_], hh[j_].z, th.z); \
        th.w = fmaf(e_[j_], hh[j_].w, th.w); \
    } \
    float sel_ = p_[0]; \
    _Pragma("unroll") \
    for (int i_ = 1; i_ < CH; ++i_) sel_ = (lane == i_) ? p_[i_] : sel_; \
    if (lane < CH) Pb[(ch) * CH + lane] = sel_; \
} while (0)

__global__ __launch_bounds__(64, 2) void theta_scan_kernel(
    const float* __restrict__ H, const float* __restrict__ Tgt,
    const float* __restrict__ theta0, const float* __restrict__ Gram,
    float* __restrict__ PT)
{
    __shared__ float HB[2][CH][DD];   // 16 KB (each row = 1 KB = one gload16)
    __shared__ float TB[2][64];       // tgt gather (slots 0..7 used)
    __shared__ float GB[2][64];       // gram (slots 0..27 used)

    const int b    = blockIdx.x & 7;     // batch -> XCD
    const int row  = blockIdx.x >> 3;    // 256 rows
    const int lane = threadIdx.x;        // owns cols lane*4 .. lane*4+3

    float4 th = *reinterpret_cast<const float4*>(
        theta0 + (size_t)row * DD + lane * 4);
    // drain th BEFORE staging so the vmcnt(10) bookkeeping is exact
    asm volatile("s_waitcnt vmcnt(0)" ::: "memory");

    const float* hbase = H    + (size_t)b * NTOK * DD + lane * 4;
    const float* tbase = Tgt  + (size_t)b * NTOK * DD + row
                              + (size_t)(lane & 7) * DD;
    const float* gbase = Gram + (size_t)b * NCHUNK * 32 + (lane & 31);
    float*       Pb    = PT   + ((size_t)b * DD + row) * NTOK;

    STAGE_CHUNK(0, 0);

    #pragma clang loop unroll(disable)
    for (int ch = 0; ch < NCHUNK; ch += 2) {
        SCAN_BODY(ch, 0);
        SCAN_BODY(ch + 1, 1);
    }
}

// ---------------------------------------------------------------------------
extern "C" void kernel_launch(void* const* d_in, const int* in_sizes, int n_in,
                              void* d_out, int out_size, void* d_ws, size_t ws_size,
                              hipStream_t stream) {
    const float* seq    = (const float*)d_in[0];
    const float* tgt    = (const float*)d_in[1];
    const float* theta0 = (const float*)d_in[2];
    const float* W_e    = (const float*)d_in[3];
    const float* W_o    = (const float*)d_in[4];
    float* out = (float*)d_out;

    float* Hbuf  = (float*)d_ws;                      // 8 MB
    float* PTbuf = Hbuf + (size_t)NB * NTOK * DD;     // 8 MB, [NB][DD][NTOK]
    float* Cbuf  = out;                                // gram scratch (128 KB)

    dim3 ggrid(NB * NTOK / GM, DD / GN);              // (64, 4)

    gemm_abt_kernel<<<ggrid, 512, 0, stream>>>(seq, W_e, Hbuf);
    gram_kernel<<<NB * NCHUNK, 128, 0, stream>>>(Hbuf, Cbuf);
    theta_scan_kernel<<<NB * 256, 64, 0, stream>>>(Hbuf, tgt, theta0, Cbuf, PTbuf);
    gemm_pt_kernel<<<ggrid, 512, 0, stream>>>(PTbuf, W_o, out);
}

// Round 10
// 235.845 us; speedup vs baseline: 1.1602x; 1.1602x over previous
//
#include <hip/hip_runtime.h>

#define LR_C 0.01f
#define NB 8
#define NTOK 1024
#define DD 256
#define CH 8
#define NCHUNK (NTOK / CH)   // 128

typedef float f32x4_t __attribute__((ext_vector_type(4)));

// DPP add: s += dpp_move(s, ctrl), bound_ctrl=true
#define DPP_ADD(x, ctrl) \
    ((x) + __int_as_float(__builtin_amdgcn_update_dpp( \
        0, __float_as_int(x), (ctrl), 0xF, 0xF, true)))

// 64-lane sum -> lane 63 (all VALU pipe; proven in R3).
// xor1, xor2, row_half_mirror, row_mirror, row_bcast15, row_bcast31.
#define REDUCE_TO63(s) do { \
    s = DPP_ADD(s, 0xB1); \
    s = DPP_ADD(s, 0x4E); \
    s = DPP_ADD(s, 0x141); \
    s = DPP_ADD(s, 0x140); \
    s = DPP_ADD(s, 0x142); \
    s = DPP_ADD(s, 0x143); \
} while (0)

// Full all-lanes sum (gram kernel only; proven R4-R9).
#define REDUCE_ALL64(s) do { \
    s = DPP_ADD(s, 0xB1); \
    s = DPP_ADD(s, 0x4E); \
    s = DPP_ADD(s, 0x141); \
    s = DPP_ADD(s, 0x140); \
    s += __shfl_xor(s, 16, 64); \
    s += __shfl_xor(s, 32, 64); \
} while (0)

// Async global->LDS staging (proven correct R6/R9).
__device__ __forceinline__ void gload16(const float* g, float* l) {
    __builtin_amdgcn_global_load_lds(
        (const __attribute__((address_space(1))) unsigned int*)g,
        (__attribute__((address_space(3))) unsigned int*)l, 16, 0, 0);
}
__device__ __forceinline__ void gload4(const float* g, float* l) {
    __builtin_amdgcn_global_load_lds(
        (const __attribute__((address_space(1))) unsigned int*)g,
        (__attribute__((address_space(3))) unsigned int*)l, 4, 0, 0);
}

// 32-bit LDS byte offset of a __shared__ object.
__device__ __forceinline__ unsigned lds_addr(const void* p) {
    return (unsigned)(unsigned long long)
        (const __attribute__((address_space(3))) char*)p;
}

// asm ds_read_b128: invisible to the compiler's vmcnt legalizer, so our
// counted s_waitcnt vmcnt(10) is not overridden with a vmcnt(0) drain.
#define DSR4(dst, base, imm) \
    asm volatile("ds_read_b128 %0, %1 offset:" imm : "=v"(dst) : "v"(base))

// ---------------------------------------------------------------------------
// GEMM1: C[m][n] = sum_k A[m][k]*B[n][k]. 128x64 tile, BK=16, 512 thr.
// (unchanged — passed R6/R9)
// ---------------------------------------------------------------------------
#define GM 128
#define GN 64
#define GK 16

__global__ __launch_bounds__(512) void gemm_abt_kernel(
    const float* __restrict__ A, const float* __restrict__ B,
    float* __restrict__ C)
{
    __shared__ float As[GK][GM + 4];
    __shared__ float Bs[GK][GN + 4];
    const int t    = threadIdx.x;
    const int arow = t >> 2, ak = (t & 3) * 4;
    const int brow = t >> 2, bk = (t & 3) * 4;
    const int tx   = t & 15, ty = t >> 4;

    const float* Ap = A + (size_t)(blockIdx.x * GM + arow) * DD + ak;
    const float* Bp = B + (size_t)(blockIdx.y * GN + (t < 256 ? brow : 0)) * DD + bk;

    float4 acc[4];
    #pragma unroll
    for (int i = 0; i < 4; ++i) acc[i] = make_float4(0.f, 0.f, 0.f, 0.f);

    float4 a0 = *reinterpret_cast<const float4*>(Ap);
    float4 b0 = *reinterpret_cast<const float4*>(Bp);

    for (int k0 = 0; k0 < DD; k0 += GK) {
        __syncthreads();
        As[ak + 0][arow] = a0.x; As[ak + 1][arow] = a0.y;
        As[ak + 2][arow] = a0.z; As[ak + 3][arow] = a0.w;
        if (t < 256) {
            Bs[bk + 0][brow] = b0.x; Bs[bk + 1][brow] = b0.y;
            Bs[bk + 2][brow] = b0.z; Bs[bk + 3][brow] = b0.w;
        }
        __syncthreads();
        if (k0 + GK < DD) {
            a0 = *reinterpret_cast<const float4*>(Ap + k0 + GK);
            b0 = *reinterpret_cast<const float4*>(Bp + k0 + GK);
        }
        #pragma unroll
        for (int k = 0; k < GK; ++k) {
            float4 av = *reinterpret_cast<const float4*>(&As[k][ty * 4]);
            float4 bv = *reinterpret_cast<const float4*>(&Bs[k][tx * 4]);
            acc[0].x = fmaf(av.x, bv.x, acc[0].x); acc[0].y = fmaf(av.x, bv.y, acc[0].y);
            acc[0].z = fmaf(av.x, bv.z, acc[0].z); acc[0].w = fmaf(av.x, bv.w, acc[0].w);
            acc[1].x = fmaf(av.y, bv.x, acc[1].x); acc[1].y = fmaf(av.y, bv.y, acc[1].y);
            acc[1].z = fmaf(av.y, bv.z, acc[1].z); acc[1].w = fmaf(av.y, bv.w, acc[1].w);
            acc[2].x = fmaf(av.z, bv.x, acc[2].x); acc[2].y = fmaf(av.z, bv.y, acc[2].y);
            acc[2].z = fmaf(av.z, bv.z, acc[2].z); acc[2].w = fmaf(av.z, bv.w, acc[2].w);
            acc[3].x = fmaf(av.w, bv.x, acc[3].x); acc[3].y = fmaf(av.w, bv.y, acc[3].y);
            acc[3].z = fmaf(av.w, bv.z, acc[3].z); acc[3].w = fmaf(av.w, bv.w, acc[3].w);
        }
    }
    #pragma unroll
    for (int i = 0; i < 4; ++i) {
        float* cp = C + (size_t)(blockIdx.x * GM + ty * 4 + i) * DD
                      + blockIdx.y * GN + tx * 4;
        *reinterpret_cast<float4*>(cp) = acc[i];
    }
}

// ---------------------------------------------------------------------------
// GEMM2: C[b*1024+t][n] = sum_k PT[b][k][t]*B[n][k]. (unchanged — passed)
// ---------------------------------------------------------------------------
__global__ __launch_bounds__(512) void gemm_pt_kernel(
    const float* __restrict__ PT, const float* __restrict__ B,
    float* __restrict__ C)
{
    __shared__ float As[GK][GM + 4];
    __shared__ float Bs[GK][GN + 4];
    const int t  = threadIdx.x;
    const int mb = blockIdx.x;
    const int b  = mb >> 3;
    const int t0 = (mb & 7) * GM;

    const int krow = t >> 5, tcol = (t & 31) * 4;
    const int brow = t >> 2, bk   = (t & 3) * 4;
    const int tx   = t & 15, ty   = t >> 4;

    const float* Ap = PT + (size_t)b * DD * NTOK + (size_t)krow * NTOK + t0 + tcol;
    const float* Bp = B + (size_t)(blockIdx.y * GN + (t < 256 ? brow : 0)) * DD + bk;

    float4 acc[4];
    #pragma unroll
    for (int i = 0; i < 4; ++i) acc[i] = make_float4(0.f, 0.f, 0.f, 0.f);

    float4 a0 = *reinterpret_cast<const float4*>(Ap);
    float4 b0 = *reinterpret_cast<const float4*>(Bp);

    for (int k0 = 0; k0 < DD; k0 += GK) {
        __syncthreads();
        *reinterpret_cast<float4*>(&As[krow][tcol]) = a0;
        if (t < 256) {
            Bs[bk + 0][brow] = b0.x; Bs[bk + 1][brow] = b0.y;
            Bs[bk + 2][brow] = b0.z; Bs[bk + 3][brow] = b0.w;
        }
        __syncthreads();
        if (k0 + GK < DD) {
            a0 = *reinterpret_cast<const float4*>(Ap + (size_t)(k0 + GK) * NTOK);
            b0 = *reinterpret_cast<const float4*>(Bp + k0 + GK);
        }
        #pragma unroll
        for (int k = 0; k < GK; ++k) {
            float4 av = *reinterpret_cast<const float4*>(&As[k][ty * 4]);
            float4 bv = *reinterpret_cast<const float4*>(&Bs[k][tx * 4]);
            acc[0].x = fmaf(av.x, bv.x, acc[0].x); acc[0].y = fmaf(av.x, bv.y, acc[0].y);
            acc[0].z = fmaf(av.x, bv.z, acc[0].z); acc[0].w = fmaf(av.x, bv.w, acc[0].w);
            acc[1].x = fmaf(av.y, bv.x, acc[1].x); acc[1].y = fmaf(av.y, bv.y, acc[1].y);
            acc[1].z = fmaf(av.y, bv.z, acc[1].z); acc[1].w = fmaf(av.y, bv.w, acc[1].w);
            acc[2].x = fmaf(av.z, bv.x, acc[2].x); acc[2].y = fmaf(av.z, bv.y, acc[2].y);
            acc[2].z = fmaf(av.z, bv.z, acc[2].z); acc[2].w = fmaf(av.z, bv.w, acc[2].w);
            acc[3].x = fmaf(av.w, bv.x, acc[3].x); acc[3].y = fmaf(av.w, bv.y, acc[3].y);
            acc[3].z = fmaf(av.w, bv.z, acc[3].z); acc[3].w = fmaf(av.w, bv.w, acc[3].w);
        }
    }
    #pragma unroll
    for (int i = 0; i < 4; ++i) {
        float* cp = C + (size_t)(b * NTOK + t0 + ty * 4 + i) * DD
                      + blockIdx.y * GN + tx * 4;
        *reinterpret_cast<float4*>(cp) = acc[i];
    }
}

// ---------------------------------------------------------------------------
// Gram: c_ij = h_i . h_j for j<i in chunk of 8 (unchanged — passed R4-R9).
// ---------------------------------------------------------------------------
__global__ __launch_bounds__(128) void gram_kernel(
    const float* __restrict__ H, float* __restrict__ Gram)
{
    const int blk  = blockIdx.x;
    const int b    = blk & 7;
    const int chk  = blk >> 3;
    const int w    = threadIdx.x >> 6;
    const int lane = threadIdx.x & 63;
    const float* Hc = H + ((size_t)b * NTOK + (size_t)chk * CH) * DD + lane * 4;

    float4 h[CH];
    #pragma unroll
    for (int i = 0; i < CH; ++i)
        h[i] = *reinterpret_cast<const float4*>(Hc + (size_t)i * DD);

    float sel = 0.f;
    #pragma unroll
    for (int i = 1; i < CH; ++i) {
        #pragma unroll
        for (int j = 0; j < i; ++j) {
            const int idx = i * (i - 1) / 2 + j;
            if ((idx & 1) == w) {
                float s = h[j].x * h[i].x;
                s = fmaf(h[j].y, h[i].y, s);
                s = fmaf(h[j].z, h[i].z, s);
                s = fmaf(h[j].w, h[i].w, s);
                REDUCE_ALL64(s);
                sel = (lane == idx) ? s : sel;
            }
        }
    }
    if (lane < 28 && (lane & 1) == w)
        Gram[((size_t)b * NCHUNK + chk) * 32 + lane] = sel;
}

// ---------------------------------------------------------------------------
// Chunked scan: 2048 blocks x 64 thr (1 wave, no barriers, XCD-swizzled).
// Stage chunk+1 via global_load_lds; COUNTED s_waitcnt vmcnt(10) (drains only
// the current chunk's stage + previous store; next stage stays in flight).
// LDS reads are asm ds_read_b128 so the compiler cannot insert vmcnt(0).
// Reduce: 6-DPP to lane 63 + readlane (VALU pipe only).
// ---------------------------------------------------------------------------
#define STAGE_CHUNK(nc, pb) do { \
    const float* hs_ = hbase + (size_t)(nc) * (CH * DD); \
    gload16(hs_ + 0 * DD, &HB[pb][0][0]); \
    gload16(hs_ + 1 * DD, &HB[pb][1][0]); \
    gload16(hs_ + 2 * DD, &HB[pb][2][0]); \
    gload16(hs_ + 3 * DD, &HB[pb][3][0]); \
    gload16(hs_ + 4 * DD, &HB[pb][4][0]); \
    gload16(hs_ + 5 * DD, &HB[pb][5][0]); \
    gload16(hs_ + 6 * DD, &HB[pb][6][0]); \
    gload16(hs_ + 7 * DD, &HB[pb][7][0]); \
    gload4(tbase + (size_t)(nc) * (CH * DD), &TB[pb][0]); \
    gload4(gbase + (size_t)(nc) * 32, &GB[pb][0]); \
} while (0)

#define SCAN_BODY(ch, par, HLDS, TLDS, GLDS) do { \
    const int nc_ = ((ch) + 1 < NCHUNK) ? (ch) + 1 : NCHUNK - 1; \
    STAGE_CHUNK(nc_, (par) ^ 1); \
    /* oldest 11 = this chunk's stage(10) + prev pred-store(1); next stage */ \
    /* (10 newest) stays in flight across this chunk's compute. */ \
    asm volatile("s_waitcnt vmcnt(10)" ::: "memory"); \
    __builtin_amdgcn_sched_barrier(0); \
    f32x4_t hh[CH]; f32x4_t tv0, tv1; f32x4_t gq[7]; \
    DSR4(hh[0], HLDS, "0");    DSR4(hh[1], HLDS, "1024"); \
    DSR4(hh[2], HLDS, "2048"); DSR4(hh[3], HLDS, "3072"); \
    DSR4(hh[4], HLDS, "4096"); DSR4(hh[5], HLDS, "5120"); \
    DSR4(hh[6], HLDS, "6144"); DSR4(hh[7], HLDS, "7168"); \
    DSR4(tv0, TLDS, "0");      DSR4(tv1, TLDS, "16"); \
    DSR4(gq[0], GLDS, "0");  DSR4(gq[1], GLDS, "16"); \
    DSR4(gq[2], GLDS, "32"); DSR4(gq[3], GLDS, "48"); \
    DSR4(gq[4], GLDS, "64"); DSR4(gq[5], GLDS, "80"); \
    DSR4(gq[6], GLDS, "96"); \
    asm volatile("s_waitcnt lgkmcnt(0)" ::: "memory"); \
    __builtin_amdgcn_sched_barrier(0);   /* rule #18 fence */ \
    float s_[CH]; \
    _Pragma("unroll") \
    for (int i_ = 0; i_ < CH; ++i_) { \
        float sv_ = hh[i_][0] * th.x; \
        sv_ = fmaf(hh[i_][1], th.y, sv_); \
        sv_ = fmaf(hh[i_][2], th.z, sv_); \
        sv_ = fmaf(hh[i_][3], th.w, sv_); \
        s_[i_] = sv_; \
    } \
    _Pragma("unroll") \
    for (int i_ = 0; i_ < CH; ++i_) { REDUCE_TO63(s_[i_]); } \
    float a_[CH]; \
    _Pragma("unroll") \
    for (int i_ = 0; i_ < CH; ++i_) \
        a_[i_] = __int_as_float( \
            __builtin_amdgcn_readlane(__float_as_int(s_[i_]), 63)); \
    float gv_[28]; \
    _Pragma("unroll") \
    for (int q_ = 0; q_ < 7; ++q_) \
        *reinterpret_cast<f32x4_t*>(&gv_[q_ * 4]) = gq[q_]; \
    float lt_[CH]; \
    *reinterpret_cast<f32x4_t*>(&lt_[0]) = tv0 * LR_C; \
    *reinterpret_cast<f32x4_t*>(&lt_[4]) = tv1 * LR_C; \
    float e_[CH], p_[CH]; \
    _Pragma("unroll") \
    for (int i_ = 0; i_ < CH; ++i_) { \
        float pv_ = a_[i_]; \
        _Pragma("unroll") \
        for (int j_ = 0; j_ < i_; ++j_) \
            pv_ = fmaf(e_[j_], gv_[i_ * (i_ - 1) / 2 + j_], pv_); \
        p_[i_] = pv_; \
        e_[i_] = fmaf(-LR_C, pv_, lt_[i_]); \
    } \
    _Pragma("unroll") \
    for (int j_ = 0; j_ < CH; ++j_) { \
        th.x = fmaf(e_[j_], hh[j_][0], th.x); \
        th.y = fmaf(e_[j_], hh[j_][1], th.y); \
        th.z = fmaf(e_[j_], hh[j_][2], th.z); \
        th.w = fmaf(e_[j_], hh[j_][3], th.w); \
    } \
    float sel_ = p_[0]; \
    _Pragma("unroll") \
    for (int i_ = 1; i_ < CH; ++i_) sel_ = (lane == i_) ? p_[i_] : sel_; \
    if (lane < CH) Pb[(ch) * CH + lane] = sel_; \
} while (0)

__global__ __launch_bounds__(64, 2) void theta_scan_kernel(
    const float* __restrict__ H, const float* __restrict__ Tgt,
    const float* __restrict__ theta0, const float* __restrict__ Gram,
    float* __restrict__ PT)
{
    __shared__ float HB[2][CH][DD];   // 16 KB (row = 1 KB = one gload16)
    __shared__ float TB[2][64];       // tgt gather (slots 0..7 used)
    __shared__ float GB[2][64];       // gram (slots 0..27 used)

    const int b    = blockIdx.x & 7;     // batch -> XCD
    const int row  = blockIdx.x >> 3;    // 256 rows
    const int lane = threadIdx.x;        // owns cols lane*4 .. lane*4+3

    float4 th = *reinterpret_cast<const float4*>(
        theta0 + (size_t)row * DD + lane * 4);
    // drain th BEFORE staging so the vmcnt(10) bookkeeping is exact
    asm volatile("s_waitcnt vmcnt(0)" ::: "memory");

    const float* hbase = H    + (size_t)b * NTOK * DD + lane * 4;
    const float* tbase = Tgt  + (size_t)b * NTOK * DD + row
                              + (size_t)(lane & 7) * DD;
    const float* gbase = Gram + (size_t)b * NCHUNK * 32 + (lane & 31);
    float*       Pb    = PT   + ((size_t)b * DD + row) * NTOK;

    const unsigned hL0 = lds_addr(&HB[0][0][0]) + lane * 16;
    const unsigned hL1 = lds_addr(&HB[1][0][0]) + lane * 16;
    const unsigned tL0 = lds_addr(&TB[0][0]);
    const unsigned tL1 = lds_addr(&TB[1][0]);
    const unsigned gL0 = lds_addr(&GB[0][0]);
    const unsigned gL1 = lds_addr(&GB[1][0]);

    STAGE_CHUNK(0, 0);

    #pragma clang loop unroll(disable)
    for (int ch = 0; ch < NCHUNK; ch += 2) {
        SCAN_BODY(ch, 0, hL0, tL0, gL0);
        SCAN_BODY(ch + 1, 1, hL1, tL1, gL1);
    }
}

// ---------------------------------------------------------------------------
extern "C" void kernel_launch(void* const* d_in, const int* in_sizes, int n_in,
                              void* d_out, int out_size, void* d_ws, size_t ws_size,
                              hipStream_t stream) {
    const float* seq    = (const float*)d_in[0];
    const float* tgt    = (const float*)d_in[1];
    const float* theta0 = (const float*)d_in[2];
    const float* W_e    = (const float*)d_in[3];
    const float* W_o    = (const float*)d_in[4];
    float* out = (float*)d_out;

    float* Hbuf  = (float*)d_ws;                      // 8 MB
    float* PTbuf = Hbuf + (size_t)NB * NTOK * DD;     // 8 MB, [NB][DD][NTOK]
    float* Cbuf  = out;                                // gram scratch (128 KB)

    dim3 ggrid(NB * NTOK / GM, DD / GN);              // (64, 4)

    gemm_abt_kernel<<<ggrid, 512, 0, stream>>>(seq, W_e, Hbuf);
    gram_kernel<<<NB * NCHUNK, 128, 0, stream>>>(Hbuf, Cbuf);
    theta_scan_kernel<<<NB * 256, 64, 0, stream>>>(Hbuf, tgt, theta0, Cbuf, PTbuf);
    gemm_pt_kernel<<<ggrid, 512, 0, stream>>>(PTbuf, W_o, out);
}